// Round 1
// baseline (504.693 us; speedup 1.0000x reference)
//
#include <hip/hip_runtime.h>
#include <hip/hip_bf16.h>
#include <cstdint>
#include <cstddef>

#define DEVI __device__ __forceinline__

typedef __attribute__((ext_vector_type(8))) short bf16x8;
typedef __attribute__((ext_vector_type(4))) float f32x4;

DEVI unsigned short f2bf(float f){
  unsigned u; __builtin_memcpy(&u, &f, 4);
  u += 0x7fffu + ((u >> 16) & 1u);
  return (unsigned short)(u >> 16);
}

DEVI f32x4 mfma_bf16(bf16x8 a, bf16x8 b, f32x4 c){
  return __builtin_amdgcn_mfma_f32_16x16x32_bf16(a, b, c, 0, 0, 0);
}

#define GLDS16(gp, lp) __builtin_amdgcn_global_load_lds( \
    (const __attribute__((address_space(1))) void*)(gp), \
    (__attribute__((address_space(3))) void*)(lp), 16, 0, 0)

// ---------------------------------------------------------------------------
// W fp32 [K=1024][N=1024] -> Wt bf16 [N][K]
__global__ __launch_bounds__(256) void transpose_w(const float* __restrict__ W,
                                                   unsigned short* __restrict__ Wt){
  __shared__ float tile[32][33];
  int bx = blockIdx.x * 32;  // n block
  int by = blockIdx.y * 32;  // k block
  int tx = threadIdx.x, ty = threadIdx.y;
  #pragma unroll
  for (int j = 0; j < 32; j += 8)
    tile[ty + j][tx] = W[(size_t)(by + ty + j) * 1024 + bx + tx];
  __syncthreads();
  #pragma unroll
  for (int j = 0; j < 32; j += 8)
    Wt[(size_t)(bx + ty + j) * 1024 + by + tx] = f2bf(tile[tx][ty + j]);
}

// ---------------------------------------------------------------------------
// LayerNorm: fp32 row[1024] -> bf16 row
__global__ __launch_bounds__(256) void ln_kernel(const float* __restrict__ x,
                                                 const float* __restrict__ g,
                                                 const float* __restrict__ b,
                                                 unsigned short* __restrict__ out){
  int row = blockIdx.x, t = threadIdx.x, lane = t & 63, wid = t >> 6;
  const float4* xr = (const float4*)(x + (size_t)row * 1024);
  float4 v = xr[t];
  float s = v.x + v.y + v.z + v.w;
  #pragma unroll
  for (int o = 32; o >= 1; o >>= 1) s += __shfl_xor(s, o, 64);
  __shared__ float red[8];
  if (lane == 0) red[wid] = s;
  __syncthreads();
  float mu = (red[0] + red[1] + red[2] + red[3]) * (1.0f / 1024.0f);
  float d0 = v.x - mu, d1 = v.y - mu, d2 = v.z - mu, d3 = v.w - mu;
  float ss = d0*d0 + d1*d1 + d2*d2 + d3*d3;
  #pragma unroll
  for (int o = 32; o >= 1; o >>= 1) ss += __shfl_xor(ss, o, 64);
  if (lane == 0) red[4 + wid] = ss;
  __syncthreads();
  float var = (red[4] + red[5] + red[6] + red[7]) * (1.0f / 1024.0f);
  float rs = rsqrtf(var + 1e-5f);
  float4 gv = ((const float4*)g)[t];
  float4 bv = ((const float4*)b)[t];
  ushort4 o4;
  o4.x = f2bf(d0 * rs * gv.x + bv.x);
  o4.y = f2bf(d1 * rs * gv.y + bv.y);
  o4.z = f2bf(d2 * rs * gv.z + bv.z);
  o4.w = f2bf(d3 * rs * gv.w + bv.w);
  *(ushort4*)(out + (size_t)row * 1024 + t * 4) = o4;
}

// ---------------------------------------------------------------------------
// GEMM: A bf16 [M][1024] x Wt bf16 [1024][1024] (+bias). EPI: 0=bf16 out,
// 1=gelu->bf16 out, 2=+res(fp32)->fp32 out.  m97 structure: 128x128 tile, BK=32.
template<int EPI>
__global__ __launch_bounds__(256) void gemm_bt(const unsigned short* __restrict__ A,
                                               const unsigned short* __restrict__ Bt,
                                               const float* __restrict__ bias,
                                               const float* __restrict__ res,
                                               void* __restrict__ outp){
  const int K = 1024, N = 1024;
  __shared__ short As[128 * 32];
  __shared__ short Bs[128 * 32];
  int t = threadIdx.x, lane = t & 63, w = t >> 6;
  int wm = w >> 1, wn = w & 1;
  int m0 = blockIdx.y * 128, n0 = blockIdx.x * 128;
  f32x4 acc[4][4] = {};
  for (int k0 = 0; k0 < K; k0 += 32){
    __syncthreads();
    #pragma unroll
    for (int j = 0; j < 2; j++){
      int c = t + j * 256;
      int r = c >> 2, col = (c & 3) * 8;
      unsigned ldsb = (unsigned)(w * 1024 + j * 4096);
      GLDS16(A  + (size_t)(m0 + r) * K + k0 + col, (char*)As + ldsb);
      GLDS16(Bt + (size_t)(n0 + r) * K + k0 + col, (char*)Bs + ldsb);
    }
    __syncthreads();
    bf16x8 af[4], bf[4];
    #pragma unroll
    for (int mi = 0; mi < 4; mi++)
      af[mi] = *(const bf16x8*)(As + (wm*64 + mi*16 + (lane & 15)) * 32 + (lane >> 4) * 8);
    #pragma unroll
    for (int ni = 0; ni < 4; ni++)
      bf[ni] = *(const bf16x8*)(Bs + (wn*64 + ni*16 + (lane & 15)) * 32 + (lane >> 4) * 8);
    #pragma unroll
    for (int mi = 0; mi < 4; mi++)
      #pragma unroll
      for (int ni = 0; ni < 4; ni++)
        acc[mi][ni] = mfma_bf16(af[mi], bf[ni], acc[mi][ni]);
  }
  #pragma unroll
  for (int mi = 0; mi < 4; mi++){
    #pragma unroll
    for (int ni = 0; ni < 4; ni++){
      #pragma unroll
      for (int r = 0; r < 4; r++){
        int row = m0 + wm*64 + mi*16 + ((lane >> 4) << 2) + r;
        int col = n0 + wn*64 + ni*16 + (lane & 15);
        float v = acc[mi][ni][r] + bias[col];
        if (EPI == 1) v = 0.5f * v * (1.0f + erff(v * 0.70710678118654752f));
        if (EPI == 2){
          v += res[(size_t)row * N + col];
          ((float*)outp)[(size_t)row * N + col] = v;
        } else {
          ((unsigned short*)outp)[(size_t)row * N + col] = f2bf(v);
        }
      }
    }
  }
}

// ---------------------------------------------------------------------------
// Flash attention: per (q-tile of 64, head, batch). Writes ctx bf16 + m,l fp32.
__global__ __launch_bounds__(256) void flash_kernel(const unsigned short* __restrict__ Q,
                                                    const unsigned short* __restrict__ Kg,
                                                    const unsigned short* __restrict__ V,
                                                    unsigned short* __restrict__ CTX,
                                                    float* __restrict__ Mo,
                                                    float* __restrict__ Lo){
  int qt = blockIdx.x, h = blockIdx.y, b = blockIdx.z;
  int q0 = qt * 64;
  __shared__ short Qs[64][72], Ks[64][72], Vts[64][72], Ps[64][72];
  int t = threadIdx.x, lane = t & 63, wid = t >> 6;
  #pragma unroll
  for (int i = 0; i < 2; i++){
    int c = t + i * 256, r = c >> 3, col = (c & 7) * 8;
    *(uint4*)&Qs[r][col] = *(const uint4*)(Q + ((size_t)((b*2048 + q0 + r)*16 + h))*64 + col);
  }
  __syncthreads();
  int qr = wid * 16 + (lane & 15);
  bf16x8 aq0 = *(const bf16x8*)&Qs[qr][(lane >> 4) * 8];
  bf16x8 aq1 = *(const bf16x8*)&Qs[qr][(lane >> 4) * 8 + 32];
  f32x4 acc[4] = {};
  float mrow[4] = {-1e30f, -1e30f, -1e30f, -1e30f};
  float lrow[4] = {0.f, 0.f, 0.f, 0.f};
  int rbase = wid * 16 + ((lane >> 4) << 2);   // local row base for this lane's 4 rows

  for (int kt = 0; kt <= qt; kt++){
    __syncthreads();
    #pragma unroll
    for (int i = 0; i < 2; i++){
      int c = t + i * 256, r = c >> 3, col = (c & 7) * 8;
      size_t gb = ((size_t)((b*2048 + kt*64 + r)*16 + h))*64 + col;
      *(uint4*)&Ks[r][col] = *(const uint4*)(Kg + gb);
      uint4 vv = *(const uint4*)(V + gb);
      unsigned short* vp = (unsigned short*)&vv;
      #pragma unroll
      for (int j2 = 0; j2 < 8; j2++) Vts[col + j2][r] = vp[j2];
    }
    __syncthreads();
    f32x4 sf[4];
    #pragma unroll
    for (int kf = 0; kf < 4; kf++){
      bf16x8 b0 = *(const bf16x8*)&Ks[kf*16 + (lane & 15)][(lane >> 4) * 8];
      bf16x8 b1 = *(const bf16x8*)&Ks[kf*16 + (lane & 15)][(lane >> 4) * 8 + 32];
      f32x4 z = {0.f, 0.f, 0.f, 0.f};
      z = mfma_bf16(aq0, b0, z);
      z = mfma_bf16(aq1, b1, z);
      sf[kf] = z;
    }
    bool diag = (kt == qt);
    #pragma unroll
    for (int kf = 0; kf < 4; kf++){
      #pragma unroll
      for (int r = 0; r < 4; r++){
        float sv = sf[kf][r] * 0.125f;
        if (diag){
          int cg = kt*64 + kf*16 + (lane & 15);
          if (cg > q0 + rbase + r) sv = -1e30f;
        }
        sf[kf][r] = sv;
      }
    }
    #pragma unroll
    for (int r = 0; r < 4; r++){
      float tm = fmaxf(fmaxf(sf[0][r], sf[1][r]), fmaxf(sf[2][r], sf[3][r]));
      #pragma unroll
      for (int o = 8; o >= 1; o >>= 1) tm = fmaxf(tm, __shfl_xor(tm, o, 64));
      float mn = fmaxf(mrow[r], tm);
      float sc = __expf(mrow[r] - mn);
      mrow[r] = mn; lrow[r] *= sc;
      #pragma unroll
      for (int df = 0; df < 4; df++) acc[df][r] *= sc;
      float ps = 0.f;
      #pragma unroll
      for (int kf = 0; kf < 4; kf++){
        float p = __expf(sf[kf][r] - mn);
        ps += p;
        Ps[rbase + r][kf*16 + (lane & 15)] = (short)f2bf(p);
      }
      #pragma unroll
      for (int o = 8; o >= 1; o >>= 1) ps += __shfl_xor(ps, o, 64);
      lrow[r] += ps;
    }
    __syncthreads();
    bf16x8 pa0 = *(const bf16x8*)&Ps[qr][(lane >> 4) * 8];
    bf16x8 pa1 = *(const bf16x8*)&Ps[qr][(lane >> 4) * 8 + 32];
    #pragma unroll
    for (int df = 0; df < 4; df++){
      bf16x8 bv0 = *(const bf16x8*)&Vts[df*16 + (lane & 15)][(lane >> 4) * 8];
      bf16x8 bv1 = *(const bf16x8*)&Vts[df*16 + (lane & 15)][(lane >> 4) * 8 + 32];
      acc[df] = mfma_bf16(pa0, bv0, acc[df]);
      acc[df] = mfma_bf16(pa1, bv1, acc[df]);
    }
  }
  #pragma unroll
  for (int r = 0; r < 4; r++){
    float inv = 1.0f / lrow[r];
    #pragma unroll
    for (int df = 0; df < 4; df++){
      int col = df*16 + (lane & 15);
      CTX[((size_t)((b*2048 + q0 + rbase + r)*16 + h))*64 + col] = f2bf(acc[df][r] * inv);
    }
    if ((lane & 15) == 0){
      size_t mi = (size_t)(b*16 + h) * 2048 + q0 + rbase + r;
      Mo[mi] = mrow[r]; Lo[mi] = lrow[r];
    }
  }
}

// ---------------------------------------------------------------------------
// Head-averaged attention probabilities. Per (k-tile, q-tile, b), loops heads.
__global__ __launch_bounds__(256) void amean_kernel(const unsigned short* __restrict__ Qg,
                                                    const unsigned short* __restrict__ Kg,
                                                    const float* __restrict__ Mo,
                                                    const float* __restrict__ Lo,
                                                    float* __restrict__ outA){
  int kt = blockIdx.x, qt = blockIdx.y, b = blockIdx.z;
  int q0 = qt * 64, k0 = kt * 64;
  int t = threadIdx.x;
  if (kt > qt){  // fully-masked tile: write zeros (d_out is poisoned)
    float4 z = {0.f, 0.f, 0.f, 0.f};
    #pragma unroll
    for (int i = 0; i < 4; i++){
      int c = t + i * 256; int r = c >> 4, col = (c & 15) * 4;
      *(float4*)(outA + (size_t)(b*2048 + q0 + r) * 2048 + k0 + col) = z;
    }
    return;
  }
  __shared__ short Qs[64][72], Ks[64][72];
  int lane = t & 63, wid = t >> 6;
  f32x4 am[4] = {};
  int rbase = wid * 16 + ((lane >> 4) << 2);
  bool diag = (kt == qt);
  for (int h = 0; h < 16; h++){
    __syncthreads();
    #pragma unroll
    for (int i = 0; i < 2; i++){
      int c = t + i * 256, r = c >> 3, col = (c & 7) * 8;
      *(uint4*)&Qs[r][col] = *(const uint4*)(Qg + ((size_t)((b*2048 + q0 + r)*16 + h))*64 + col);
      *(uint4*)&Ks[r][col] = *(const uint4*)(Kg + ((size_t)((b*2048 + k0 + r)*16 + h))*64 + col);
    }
    __syncthreads();
    int qr = wid * 16 + (lane & 15);
    bf16x8 a0 = *(const bf16x8*)&Qs[qr][(lane >> 4) * 8];
    bf16x8 a1 = *(const bf16x8*)&Qs[qr][(lane >> 4) * 8 + 32];
    float mh[4], lh[4];
    #pragma unroll
    for (int r = 0; r < 4; r++){
      size_t mi = (size_t)(b*16 + h) * 2048 + q0 + rbase + r;
      mh[r] = Mo[mi]; lh[r] = 1.0f / Lo[mi];
    }
    #pragma unroll
    for (int kf = 0; kf < 4; kf++){
      bf16x8 b0 = *(const bf16x8*)&Ks[kf*16 + (lane & 15)][(lane >> 4) * 8];
      bf16x8 b1 = *(const bf16x8*)&Ks[kf*16 + (lane & 15)][(lane >> 4) * 8 + 32];
      f32x4 z = {0.f, 0.f, 0.f, 0.f};
      z = mfma_bf16(a0, b0, z);
      z = mfma_bf16(a1, b1, z);
      #pragma unroll
      for (int r = 0; r < 4; r++){
        float sv = z[r] * 0.125f;
        float a;
        int cg = k0 + kf*16 + (lane & 15);
        if (diag && cg > q0 + rbase + r) a = 0.f;
        else a = __expf(sv - mh[r]) * lh[r];
        am[kf][r] += a * 0.0625f;
      }
    }
  }
  #pragma unroll
  for (int kf = 0; kf < 4; kf++)
    #pragma unroll
    for (int r = 0; r < 4; r++)
      outA[(size_t)(b*2048 + q0 + rbase + r) * 2048 + k0 + kf*16 + (lane & 15)] = am[kf][r];
}

// ---------------------------------------------------------------------------
extern "C" void kernel_launch(void* const* d_in, const int* in_sizes, int n_in,
                              void* d_out, int out_size, void* d_ws, size_t ws_size,
                              hipStream_t stream){
  const float* x   = (const float*)d_in[0];
  const float* Wq  = (const float*)d_in[1];
  const float* bq  = (const float*)d_in[2];
  const float* Wk  = (const float*)d_in[3];
  const float* bk  = (const float*)d_in[4];
  const float* Wv  = (const float*)d_in[5];
  const float* bv  = (const float*)d_in[6];
  const float* Wo  = (const float*)d_in[7];
  const float* bo  = (const float*)d_in[8];
  const float* g1  = (const float*)d_in[9];
  const float* b1  = (const float*)d_in[10];
  const float* g2  = (const float*)d_in[11];
  const float* b2  = (const float*)d_in[12];
  const float* Wm1 = (const float*)d_in[13];
  const float* bm1 = (const float*)d_in[14];
  const float* Wm2 = (const float*)d_in[15];
  const float* bm2 = (const float*)d_in[16];

  char* ws = (char*)d_ws;
  const size_t MB = (size_t)1 << 20;
  unsigned short* wtq  = (unsigned short*)(ws + 0*MB);
  unsigned short* wtk  = (unsigned short*)(ws + 2*MB);
  unsigned short* wtv  = (unsigned short*)(ws + 4*MB);
  unsigned short* wto  = (unsigned short*)(ws + 6*MB);
  unsigned short* wtm1 = (unsigned short*)(ws + 8*MB);
  unsigned short* wtm2 = (unsigned short*)(ws + 10*MB);
  unsigned short* o    = (unsigned short*)(ws + 12*MB);
  unsigned short* qb   = (unsigned short*)(ws + 20*MB);
  unsigned short* kb   = (unsigned short*)(ws + 28*MB);
  unsigned short* vb   = (unsigned short*)(ws + 36*MB);
  unsigned short* ctx  = (unsigned short*)(ws + 44*MB);
  float* mbuf = (float*)(ws + 52*MB);
  float* lbuf = (float*)(ws + 52*MB + 256*1024);
  float* x2   = (float*)(ws + 53*MB);
  unsigned short* hin = vb;   // reuse: v dead after flash
  unsigned short* h1  = qb;   // reuse: q dead after amean

  float* outX = (float*)d_out;
  float* outA = outX + (size_t)2*2048*1024;

  dim3 tt(32, 8);
  transpose_w<<<dim3(32,32), tt, 0, stream>>>(Wq,  wtq);
  transpose_w<<<dim3(32,32), tt, 0, stream>>>(Wk,  wtk);
  transpose_w<<<dim3(32,32), tt, 0, stream>>>(Wv,  wtv);
  transpose_w<<<dim3(32,32), tt, 0, stream>>>(Wo,  wto);
  transpose_w<<<dim3(32,32), tt, 0, stream>>>(Wm1, wtm1);
  transpose_w<<<dim3(32,32), tt, 0, stream>>>(Wm2, wtm2);

  ln_kernel<<<4096, 256, 0, stream>>>(x, g1, b1, o);

  gemm_bt<0><<<dim3(8,32), 256, 0, stream>>>(o, wtq, bq, nullptr, qb);
  gemm_bt<0><<<dim3(8,32), 256, 0, stream>>>(o, wtk, bk, nullptr, kb);
  gemm_bt<0><<<dim3(8,32), 256, 0, stream>>>(o, wtv, bv, nullptr, vb);

  flash_kernel<<<dim3(32,16,2), 256, 0, stream>>>(qb, kb, vb, ctx, mbuf, lbuf);
  amean_kernel<<<dim3(32,32,2), 256, 0, stream>>>(qb, kb, mbuf, lbuf, outA);

  gemm_bt<2><<<dim3(8,32), 256, 0, stream>>>(ctx, wto, bo, x, (void*)x2);
  ln_kernel<<<4096, 256, 0, stream>>>(x2, g2, b2, hin);
  gemm_bt<1><<<dim3(8,32), 256, 0, stream>>>(hin, wtm1, bm1, nullptr, h1);
  gemm_bt<2><<<dim3(8,32), 256, 0, stream>>>(h1, wtm2, bm2, x2, (void*)outX);
}